// Round 1
// baseline (229.149 us; speedup 1.0000x reference)
//
#include <hip/hip_runtime.h>
#include <math.h>

// EulerRosenbrockModel: B=512, D=256, HID=1024, h=0.01
// out = v + 0.005 * W2 (s ⊙ (W1 vb)),  s = 1-t^2, t = tanh(W1 y + b1), v = W2 t + b2
// (Neumann truncation of (I-cJ)^{-1}(I+dJ), exact to ~1e-5 — verified R1-R7.)
//
// R8: FULL FUSION. The chain is row-parallel (no cross-row coupling), so the
// 4-dispatch structure (3 full-GPU drains at ~16 us each) is unnecessary:
//   D1: convert W1,W2 fp32 -> bf16 in workspace (1 MB), 256 blocks, ~1 us
//   D2: fused chain, 32 blocks x 512 thr, each block owns 16 batch rows and
//       streams W1b,W2b twice (2 MB/block) through a 66 KB LDS staging buffer.
//       All intermediates (t, v, vb, p) live in LDS; zero intermediate global
//       traffic; zero inter-block sync.
// Per-chunk software pipeline: ds_write(chunk c) -> issue global loads(c+1)
// -> barrier -> MFMA(c), so HBM/L2 latency hides under the MFMA phase.
// MFMA fragment addressing identical to verified R7 (4-bank-shift pads).

#define B_SZ 512
#define D_SZ 256
#define HID_SZ 1024

typedef short short8 __attribute__((ext_vector_type(8)));   // 8 bf16 (4 VGPRs)
typedef float f32x4 __attribute__((ext_vector_type(4)));

__device__ __forceinline__ float bf16_to_f32(unsigned short u) {
    union { unsigned int i; float f; } c; c.i = ((unsigned int)u) << 16; return c.f;
}
__device__ __forceinline__ unsigned short f32_to_bf16(float f) {
    union { float f; unsigned int i; } c; c.f = f;
    unsigned int b = c.i + 0x7FFFu + ((c.i >> 16) & 1u);   // RNE
    return (unsigned short)(b >> 16);
}
__device__ __forceinline__ uint4 pack8(float4 lo, float4 hi) {
    union { unsigned short u[8]; uint4 v; } o;
    o.u[0] = f32_to_bf16(lo.x); o.u[1] = f32_to_bf16(lo.y);
    o.u[2] = f32_to_bf16(lo.z); o.u[3] = f32_to_bf16(lo.w);
    o.u[4] = f32_to_bf16(hi.x); o.u[5] = f32_to_bf16(hi.y);
    o.u[6] = f32_to_bf16(hi.z); o.u[7] = f32_to_bf16(hi.w);
    return o.v;
}

// ---- D1: W1 [1024][256] + W2 [256][1024] fp32 -> bf16. 65536 threads x 8 elems.
__global__ __launch_bounds__(256)
void convert_w(const float* __restrict__ W1, const float* __restrict__ W2,
               unsigned short* __restrict__ W1b, unsigned short* __restrict__ W2b)
{
    int t = blockIdx.x * 256 + threadIdx.x;
    const float* src; unsigned short* dst;
    if (t < 32768) { src = W1 + (size_t)t * 8; dst = W1b + (size_t)t * 8; }
    else { int u = t - 32768; src = W2 + (size_t)u * 8; dst = W2b + (size_t)u * 8; }
    float4 lo = *(const float4*)src;
    float4 hi = *(const float4*)(src + 4);
    *(uint4*)dst = pack8(lo, hi);
}

// ---- D2: fused chain. Block b owns rows bm..bm+15.
// 32 chunks of [128 weight-rows x 256 k] bf16 staged in Wst:
//   chunks  0..7  : W1b pass 1 (phase 1: t = tanh(Y@W1^T + b1) -> T)
//   chunks  8..15 : W2b pass 1 (phase 2: v = T@W2^T + b2 -> V fp32, vb -> Av)
//   chunks 16..23 : W1b pass 2 (phase 3: p = (1-t^2) ⊙ (Av@W1^T) -> T in place)
//   chunks 24..31 : W2b pass 2 (phase 4: OUT = V + 0.005 * T@W2^T)
__global__ __launch_bounds__(512)
void fused_chain(const float* __restrict__ Y,
                 const unsigned short* __restrict__ W1b,
                 const unsigned short* __restrict__ W2b,
                 const float* __restrict__ b1,
                 const float* __restrict__ b2,
                 float* __restrict__ OUT)
{
    __shared__ alignas(16) unsigned short Wst[128][264];  // 66.0 KB, stride 528B (4-bank shift)
    __shared__ alignas(16) unsigned short T[16][1032];    // 32.3 KB, stride 2064B (4-bank shift)
    __shared__ alignas(16) unsigned short Av[16][264];    //  8.3 KB (Y tile, then vb)
    __shared__ alignas(16) float V[16][264];              // 16.5 KB (v fp32)   total 123 KB

    const int tid  = threadIdx.x;
    const int wid  = tid >> 6, lane = tid & 63;
    const int l16  = lane & 15, quad = lane >> 4;
    const int bm   = blockIdx.x * 16;

    // stage Y tile [16][256] fp32 -> bf16 Av (512 units of 8, one per thread)
    {
        int row = tid >> 5, col = (tid & 31) * 8;
        const float* src = &Y[(size_t)(bm + row) * D_SZ + col];
        float4 lo = *(const float4*)src;
        float4 hi = *(const float4*)(src + 4);
        *(uint4*)&Av[row][col] = pack8(lo, hi);
    }

    uint4 pf[8];   // prefetch regs: 128x256 bf16 chunk = 8 x 16B per thread
    auto prefetch = [&](int c) {
        const int ph = c >> 3, cc = c & 7;
#pragma unroll
        for (int l = 0; l < 8; ++l) {
            int q = l * 512 + tid;
            int row = q >> 5, col = (q & 31) * 8;
            const unsigned short* src;
            if (!(ph & 1)) {                       // W1b chunk: rows cc*128..+128, k 0..256
                src = &W1b[(size_t)(cc * 128 + row) * D_SZ + col];
            } else {                               // W2b chunk: n-half h, k-quarter kq
                int h = cc >> 2, kq = cc & 3;
                src = &W2b[(size_t)(h * 128 + row) * HID_SZ + kq * 256 + col];
            }
            pf[l] = *(const uint4*)src;
        }
    };
    prefetch(0);

    f32x4 acc = {0.f, 0.f, 0.f, 0.f};
    for (int c = 0; c < 32; ++c) {
        const int ph = c >> 3, cc = c & 7;
        const int typeB = ph & 1;
        const int h = cc >> 2, kq = cc & 3;

        __syncthreads();                           // Wst free (prev chunk's MFMA done)
#pragma unroll
        for (int l = 0; l < 8; ++l) {              // regs -> LDS (waits vmcnt for pf)
            int q = l * 512 + tid;
            int row = q >> 5, col = (q & 31) * 8;
            *(uint4*)&Wst[row][col] = pf[l];
        }
        if (c + 1 < 32) prefetch(c + 1);           // issue next chunk's loads early
        __syncthreads();                           // Wst(c) visible to all waves

        if (!typeB) {
            // ---- hid-major gemm: out tile [16 m, 16 hid] per wave, K=256
            acc = {0.f, 0.f, 0.f, 0.f};
#pragma unroll
            for (int ks = 0; ks < 256; ks += 32) {
                short8 a = *(const short8*)&Av[l16][ks + quad * 8];
                short8 b = *(const short8*)&Wst[wid * 16 + l16][ks + quad * 8];
                acc = __builtin_amdgcn_mfma_f32_16x16x32_bf16(a, b, acc, 0, 0, 0);
            }
            const int col = cc * 128 + wid * 16 + l16;   // hid index
            if (ph == 0) {                          // phase 1: t = tanh(. + b1)
                const float bias = b1[col];
#pragma unroll
                for (int r = 0; r < 4; ++r)
                    T[quad * 4 + r][col] = f32_to_bf16(tanhf(acc[r] + bias));
            } else {                                // phase 3: p = (1-t^2) * .  (in place)
#pragma unroll
                for (int r = 0; r < 4; ++r) {
                    float tt = bf16_to_f32(T[quad * 4 + r][col]);
                    T[quad * 4 + r][col] = f32_to_bf16((1.f - tt * tt) * acc[r]);
                }
            }
        } else {
            // ---- n-major gemm: out tile [16 m, 16 n] per wave, K=1024 over 4 kq-chunks
            if (kq == 0) acc = {0.f, 0.f, 0.f, 0.f};
#pragma unroll
            for (int ks = 0; ks < 256; ks += 32) {
                short8 a = *(const short8*)&T[l16][kq * 256 + ks + quad * 8];
                short8 b = *(const short8*)&Wst[wid * 16 + l16][ks + quad * 8];
                acc = __builtin_amdgcn_mfma_f32_16x16x32_bf16(a, b, acc, 0, 0, 0);
            }
            if (kq == 3) {
                const int n = h * 128 + wid * 16 + l16;  // output col
                if (ph == 1) {                      // phase 2: v = . + b2 -> V, vb -> Av
                    const float bb = b2[n];
#pragma unroll
                    for (int r = 0; r < 4; ++r) {
                        float v = acc[r] + bb;
                        V[quad * 4 + r][n]  = v;
                        Av[quad * 4 + r][n] = f32_to_bf16(v);
                    }
                } else {                            // phase 4: OUT = V + 0.005 * .
#pragma unroll
                    for (int r = 0; r < 4; ++r) {
                        int m = quad * 4 + r;
                        OUT[(size_t)(bm + m) * D_SZ + n] = V[m][n] + 0.005f * acc[r];
                    }
                }
            }
        }
    }
}

extern "C" void kernel_launch(void* const* d_in, const int* in_sizes, int n_in,
                              void* d_out, int out_size, void* d_ws, size_t ws_size,
                              hipStream_t stream) {
    const float* Y  = (const float*)d_in[0];  // (512, 256)
    const float* W1 = (const float*)d_in[1];  // (1024, 256)
    const float* b1 = (const float*)d_in[2];  // (1024,)
    const float* W2 = (const float*)d_in[3];  // (256, 1024)
    const float* b2 = (const float*)d_in[4];  // (256,)
    float* OUT = (float*)d_out;               // (512, 256)

    unsigned short* W1b = (unsigned short*)d_ws;                 // [1024][256] bf16, 512 KB
    unsigned short* W2b = W1b + (size_t)HID_SZ * D_SZ;           // [256][1024] bf16, 512 KB

    convert_w<<<256, 256, 0, stream>>>(W1, W2, W1b, W2b);
    fused_chain<<<32, 512, 0, stream>>>(Y, W1b, W2b, b1, b2, OUT);
}

// Round 2
// 225.259 us; speedup vs baseline: 1.0173x; 1.0173x over previous
//
#include <hip/hip_runtime.h>
#include <math.h>

// EulerRosenbrockModel: B=512, D=256, HID=1024, h=0.01
// out = v + 0.005 * W2 (s ⊙ (W1 vb)),  s = 1-t^2, t = tanh(W1 y + b1), v = W2 t + b2
// (Neumann truncation of (I-cJ)^{-1}(I+dJ), exact to ~1e-5 — verified R1-R7.)
//
// R9: fused chain (R8 structure) with the barrier-drain bug fixed.
// R8 post-mortem: __syncthreads() forces s_waitcnt vmcnt(0) before s_barrier
// (HIP compiler semantics), so the chunk-(c+1) prefetch was drained at the
// very next barrier -> zero pipeline depth -> 5.4us/chunk of exposed latency.
// Fix (T3/T4 pattern): raw __builtin_amdgcn_s_barrier() + explicit
// lgkmcnt(0) asm (cross-wave LDS visibility only); vmcnt waits are left to
// the compiler's counted per-register dependencies. Depth-2 prefetch with
// two statically-named register buffers (rule-20: no runtime indexing).
//   D1: convert W1,W2 fp32 -> bf16 (1 MB workspace), 256 blocks
//   D2: fused chain, 32 blocks x 512 thr, 16 rows/block, 32 chunks of
//       [128 w-rows x 256 k] staged via regs -> LDS; t/v/vb/p all in LDS.

#define B_SZ 512
#define D_SZ 256
#define HID_SZ 1024

typedef short short8 __attribute__((ext_vector_type(8)));   // 8 bf16 (4 VGPRs)
typedef float f32x4 __attribute__((ext_vector_type(4)));

__device__ __forceinline__ float bf16_to_f32(unsigned short u) {
    union { unsigned int i; float f; } c; c.i = ((unsigned int)u) << 16; return c.f;
}
__device__ __forceinline__ unsigned short f32_to_bf16(float f) {
    union { float f; unsigned int i; } c; c.f = f;
    unsigned int b = c.i + 0x7FFFu + ((c.i >> 16) & 1u);   // RNE
    return (unsigned short)(b >> 16);
}
__device__ __forceinline__ uint4 pack8(float4 lo, float4 hi) {
    union { unsigned short u[8]; uint4 v; } o;
    o.u[0] = f32_to_bf16(lo.x); o.u[1] = f32_to_bf16(lo.y);
    o.u[2] = f32_to_bf16(lo.z); o.u[3] = f32_to_bf16(lo.w);
    o.u[4] = f32_to_bf16(hi.x); o.u[5] = f32_to_bf16(hi.y);
    o.u[6] = f32_to_bf16(hi.z); o.u[7] = f32_to_bf16(hi.w);
    return o.v;
}
__device__ __forceinline__ float fast_tanh(float x) {
    // tanh(x) = 1 - 2/(e^{2x}+1); exact at +-inf, error ~ulp-level << bf16 storage
    float e = __expf(2.0f * x);
    return 1.0f - 2.0f / (e + 1.0f);
}
// Raw barrier: NO vmcnt drain (prefetch loads stay in flight across it).
// lgkmcnt(0) gives cross-wave visibility of this wave's ds_writes.
__device__ __forceinline__ void bar_lgkm() {
    asm volatile("s_waitcnt lgkmcnt(0)" ::: "memory");
    __builtin_amdgcn_s_barrier();
    asm volatile("" ::: "memory");
}

// ---- D1: W1 [1024][256] + W2 [256][1024] fp32 -> bf16. 65536 threads x 8 elems.
__global__ __launch_bounds__(256)
void convert_w(const float* __restrict__ W1, const float* __restrict__ W2,
               unsigned short* __restrict__ W1b, unsigned short* __restrict__ W2b)
{
    int t = blockIdx.x * 256 + threadIdx.x;
    const float* src; unsigned short* dst;
    if (t < 32768) { src = W1 + (size_t)t * 8; dst = W1b + (size_t)t * 8; }
    else { int u = t - 32768; src = W2 + (size_t)u * 8; dst = W2b + (size_t)u * 8; }
    float4 lo = *(const float4*)src;
    float4 hi = *(const float4*)(src + 4);
    *(uint4*)dst = pack8(lo, hi);
}

// ---- D2: fused chain. Block b owns rows bm..bm+15.
// 32 chunks of [128 weight-rows x 256 k] bf16 staged in Wst:
//   chunks  0..7  : W1b pass 1 (phase 0: t = tanh(Y@W1^T + b1) -> T)
//   chunks  8..15 : W2b pass 1 (phase 1: v = T@W2^T + b2 -> V fp32, vb -> Av)
//   chunks 16..23 : W1b pass 2 (phase 2: p = (1-t^2) ⊙ (Av@W1^T) -> T in place)
//   chunks 24..31 : W2b pass 2 (phase 3: OUT = V + 0.005 * T@W2^T)
__global__ __launch_bounds__(512)
void fused_chain(const float* __restrict__ Y,
                 const unsigned short* __restrict__ W1b,
                 const unsigned short* __restrict__ W2b,
                 const float* __restrict__ b1,
                 const float* __restrict__ b2,
                 float* __restrict__ OUT)
{
    __shared__ alignas(16) unsigned short Wst[128][264];  // 66.0 KB, stride 528B (4-bank shift)
    __shared__ alignas(16) unsigned short T[16][1032];    // 32.3 KB, stride 2064B (4-bank shift)
    __shared__ alignas(16) unsigned short Av[16][264];    //  8.3 KB (Y tile, then vb)
    __shared__ alignas(16) float V[16][264];              // 16.5 KB (v fp32)   total 123 KB

    const int tid  = threadIdx.x;
    const int wid  = tid >> 6, lane = tid & 63;
    const int l16  = lane & 15, quad = lane >> 4;
    const int bm   = blockIdx.x * 16;

    // stage Y tile [16][256] fp32 -> bf16 Av (512 units of 8, one per thread)
    {
        int row = tid >> 5, col = (tid & 31) * 8;
        const float* src = &Y[(size_t)(bm + row) * D_SZ + col];
        float4 lo = *(const float4*)src;
        float4 hi = *(const float4*)(src + 4);
        *(uint4*)&Av[row][col] = pack8(lo, hi);
    }

    // depth-2 prefetch, statically named buffers (rule-20: no runtime indexing)
    uint4 pfA[8], pfB[8];

#define ISSUE(BUF, C) do {                                                  \
        const int ph_ = (C) >> 3, cc_ = (C) & 7;                            \
        _Pragma("unroll")                                                   \
        for (int l = 0; l < 8; ++l) {                                       \
            int q = l * 512 + tid;                                          \
            int row = q >> 5, col = (q & 31) * 8;                           \
            const unsigned short* src;                                      \
            if (!(ph_ & 1)) {                                               \
                src = &W1b[(size_t)(cc_ * 128 + row) * D_SZ + col];         \
            } else {                                                        \
                int hh = cc_ >> 2, kqq = cc_ & 3;                           \
                src = &W2b[(size_t)(hh * 128 + row) * HID_SZ + kqq * 256 + col]; \
            }                                                               \
            BUF[l] = *(const uint4*)src;                                    \
        } } while (0)

#define STORE_WST(BUF) do {                                                 \
        _Pragma("unroll")                                                   \
        for (int l = 0; l < 8; ++l) {                                       \
            int q = l * 512 + tid;                                          \
            int row = q >> 5, col = (q & 31) * 8;                           \
            *(uint4*)&Wst[row][col] = BUF[l];                               \
        } } while (0)

    ISSUE(pfA, 0);
    ISSUE(pfB, 1);

    f32x4 acc = {0.f, 0.f, 0.f, 0.f};
    for (int c = 0; c < 32; ++c) {
        const int ph = c >> 3, cc = c & 7;
        const int typeB = ph & 1;
        const int h = cc >> 2, kq = cc & 3;

        // barrier 1: all waves done with Wst(c-1) MFMA; prev epilogue LDS visible
        bar_lgkm();
        // compiler inserts counted vmcnt waits for the buffer being consumed;
        // the other buffer's 8 loads stay in flight across the raw barriers.
        if ((c & 1) == 0) {
            STORE_WST(pfA);
            if (c + 2 < 32) ISSUE(pfA, c + 2);
        } else {
            STORE_WST(pfB);
            if (c + 2 < 32) ISSUE(pfB, c + 2);
        }
        // barrier 2: Wst(c) visible to all waves
        bar_lgkm();

        if (!typeB) {
            // ---- hid-major gemm: out tile [16 m, 16 hid] per wave, K=256
            acc = (f32x4){0.f, 0.f, 0.f, 0.f};
#pragma unroll
            for (int ks = 0; ks < 256; ks += 32) {
                short8 a = *(const short8*)&Av[l16][ks + quad * 8];
                short8 b = *(const short8*)&Wst[wid * 16 + l16][ks + quad * 8];
                acc = __builtin_amdgcn_mfma_f32_16x16x32_bf16(a, b, acc, 0, 0, 0);
            }
            const int col = cc * 128 + wid * 16 + l16;   // hid index
            if (ph == 0) {                          // phase 0: t = tanh(. + b1)
                const float bias = b1[col];
#pragma unroll
                for (int r = 0; r < 4; ++r)
                    T[quad * 4 + r][col] = f32_to_bf16(fast_tanh(acc[r] + bias));
            } else {                                // phase 2: p = (1-t^2) * .  (in place)
#pragma unroll
                for (int r = 0; r < 4; ++r) {
                    float tt = bf16_to_f32(T[quad * 4 + r][col]);
                    T[quad * 4 + r][col] = f32_to_bf16((1.f - tt * tt) * acc[r]);
                }
            }
        } else {
            // ---- n-major gemm: out tile [16 m, 16 n] per wave, K=1024 over 4 kq-chunks
            if (kq == 0) acc = (f32x4){0.f, 0.f, 0.f, 0.f};
#pragma unroll
            for (int ks = 0; ks < 256; ks += 32) {
                short8 a = *(const short8*)&T[l16][kq * 256 + ks + quad * 8];
                short8 b = *(const short8*)&Wst[wid * 16 + l16][ks + quad * 8];
                acc = __builtin_amdgcn_mfma_f32_16x16x32_bf16(a, b, acc, 0, 0, 0);
            }
            if (kq == 3) {
                const int n = h * 128 + wid * 16 + l16;  // output col
                if (ph == 1) {                      // phase 1: v = . + b2 -> V, vb -> Av
                    const float bb = b2[n];
#pragma unroll
                    for (int r = 0; r < 4; ++r) {
                        float v = acc[r] + bb;
                        V[quad * 4 + r][n]  = v;
                        Av[quad * 4 + r][n] = f32_to_bf16(v);
                    }
                } else {                            // phase 3: OUT = V + 0.005 * .
#pragma unroll
                    for (int r = 0; r < 4; ++r) {
                        int m = quad * 4 + r;
                        OUT[(size_t)(bm + m) * D_SZ + n] = V[m][n] + 0.005f * acc[r];
                    }
                }
            }
        }
    }
#undef ISSUE
#undef STORE_WST
}

extern "C" void kernel_launch(void* const* d_in, const int* in_sizes, int n_in,
                              void* d_out, int out_size, void* d_ws, size_t ws_size,
                              hipStream_t stream) {
    const float* Y  = (const float*)d_in[0];  // (512, 256)
    const float* W1 = (const float*)d_in[1];  // (1024, 256)
    const float* b1 = (const float*)d_in[2];  // (1024,)
    const float* W2 = (const float*)d_in[3];  // (256, 1024)
    const float* b2 = (const float*)d_in[4];  // (256,)
    float* OUT = (float*)d_out;               // (512, 256)

    unsigned short* W1b = (unsigned short*)d_ws;                 // [1024][256] bf16, 512 KB
    unsigned short* W2b = W1b + (size_t)HID_SZ * D_SZ;           // [256][1024] bf16, 512 KB

    convert_w<<<256, 256, 0, stream>>>(W1, W2, W1b, W2b);
    fused_chain<<<32, 512, 0, stream>>>(Y, W1b, W2b, b1, b2, OUT);
}

// Round 3
// 145.784 us; speedup vs baseline: 1.5718x; 1.5452x over previous
//
#include <hip/hip_runtime.h>
#include <math.h>

// EulerRosenbrockModel: B=512, D=256, HID=1024, h=0.01
// out = v + 0.005 * W2 (s ⊙ (W1 vb)),  s = 1-t^2, t = tanh(W1 y + b1), v = W2 t + b2
// (Neumann truncation of (I-cJ)^{-1}(I+dJ), exact to ~1e-5 — verified R1-R9.)
//
// R10: wave-autonomous fused chain. R8/R9 post-mortem: lockstep LDS staging of
// weights forced 2 barriers/chunk and a prefetch register pipeline the compiler
// mangled (all pipes <1% busy, 12.4k cy/chunk vs 2.5k of work; WRITE_SIZE 9x
// output = spill suspicion). Weights have ZERO reuse within a block, so staging
// them through LDS buys only coalescing. Instead:
//   D1 convert_w: fp32 weights -> bf16 in MFMA-FRAGMENT ORDER (one contiguous
//      1KB line per (tile,k-slice) fragment; lane l's 16B at offset l*16).
//   D2 fused_chain: 32 blocks x 512 thr, 16 rows/block. Each wave loads its
//      B-fragments DIRECTLY global->VGPR (perfectly coalesced, wave-uniform
//      base + lane*16) and MFMAs. No weight LDS, no asm, 4 barriers total
//      (only at true data deps: Ystage->ph0, t->v, v->p, p->out). Latency
//      hidden by ILP: every phase exposes 64+ independent 1KB loads per wave.
// Intermediates t/v/vb/p stay in LDS (57 KB). Fragment mapping identical to
// R7-verified layout: A/B lane holds row=(l&15), k=(l>>4)*8..+8; C/D lane r:
// m=quad*4+r, n=l16.

#define B_SZ 512
#define D_SZ 256
#define HID_SZ 1024

typedef short short8 __attribute__((ext_vector_type(8)));   // 8 bf16 (4 VGPRs)
typedef float f32x4 __attribute__((ext_vector_type(4)));

__device__ __forceinline__ float bf16_to_f32(unsigned short u) {
    union { unsigned int i; float f; } c; c.i = ((unsigned int)u) << 16; return c.f;
}
__device__ __forceinline__ unsigned short f32_to_bf16(float f) {
    union { float f; unsigned int i; } c; c.f = f;
    unsigned int b = c.i + 0x7FFFu + ((c.i >> 16) & 1u);   // RNE
    return (unsigned short)(b >> 16);
}
__device__ __forceinline__ uint4 pack8(float4 lo, float4 hi) {
    union { unsigned short u[8]; uint4 v; } o;
    o.u[0] = f32_to_bf16(lo.x); o.u[1] = f32_to_bf16(lo.y);
    o.u[2] = f32_to_bf16(lo.z); o.u[3] = f32_to_bf16(lo.w);
    o.u[4] = f32_to_bf16(hi.x); o.u[5] = f32_to_bf16(hi.y);
    o.u[6] = f32_to_bf16(hi.z); o.u[7] = f32_to_bf16(hi.w);
    return o.v;
}
__device__ __forceinline__ float fast_tanh(float x) {
    // tanh(x) = 1 - 2/(e^{2x}+1); exactness at +-inf, err << bf16 rounding
    float e = __expf(2.0f * x);
    return 1.0f - 2.0f / (e + 1.0f);
}
__device__ __forceinline__ short8 as_short8(uint4 u) {
    union { uint4 v; short8 s; } c; c.v = u; return c.s;
}

// ---- D1: swizzle weights into fragment order, fp32 -> bf16.
// W1s: frag f1 = t1*8 + ks8   (t1 in [0,64): hid tile, ks8 in [0,8): k-slice)
//      lane l holds W1[t1*16 + (l&15)][ks8*32 + (l>>4)*8 .. +8]  -> 16B at f1*1024 + l*16
// W2s: frag f2 = t2*32 + ks8  (t2 in [0,16): out-col tile, ks8 in [0,32))
//      lane l holds W2[t2*16 + (l&15)][ks8*32 + (l>>4)*8 .. +8]  -> 16B at f2*1024 + l*16
// 1024 frags total, one wave per frag: 256 blocks x 256 thr.
__global__ __launch_bounds__(256)
void convert_w(const float* __restrict__ W1, const float* __restrict__ W2,
               uint4* __restrict__ W1s, uint4* __restrict__ W2s)
{
    const int wid  = threadIdx.x >> 6, lane = threadIdx.x & 63;
    const int l16  = lane & 15, quad = lane >> 4;
    const int frag = blockIdx.x * 4 + wid;         // 0..1023
    const float* src;
    uint4* dst;
    if (frag < 512) {
        int t1 = frag >> 3, ks8 = frag & 7;
        src = &W1[(size_t)(t1 * 16 + l16) * D_SZ + ks8 * 32 + quad * 8];
        dst = &W1s[(size_t)frag * 64 + lane];
    } else {
        int f2 = frag - 512;
        int t2 = f2 >> 5, ks8 = f2 & 31;
        src = &W2[(size_t)(t2 * 16 + l16) * HID_SZ + ks8 * 32 + quad * 8];
        dst = &W2s[(size_t)f2 * 64 + lane];
    }
    float4 lo = *(const float4*)src;
    float4 hi = *(const float4*)(src + 4);
    *dst = pack8(lo, hi);
}

// ---- D2: fused chain. Block owns rows bm..bm+15; wave w owns
// hid cols w*128..+128 (ph0/ph2) and out cols w*32..+32 (ph1/ph3).
__global__ __launch_bounds__(512)
void fused_chain(const float* __restrict__ Y,
                 const uint4* __restrict__ W1s,
                 const uint4* __restrict__ W2s,
                 const float* __restrict__ b1,
                 const float* __restrict__ b2,
                 float* __restrict__ OUT)
{
    __shared__ alignas(16) unsigned short Av[16][264];   //  8.3 KB  Y bf16, then vb
    __shared__ alignas(16) unsigned short T[16][1032];   // 32.3 KB  t, then p
    __shared__ alignas(16) float V[16][264];             // 16.5 KB  v fp32   (57 KB)

    const int tid  = threadIdx.x;
    const int wid  = tid >> 6, lane = tid & 63;
    const int l16  = lane & 15, quad = lane >> 4;
    const int bm   = blockIdx.x * 16;

    // stage Y tile [16][256] fp32 -> bf16 (one 8-elem unit per thread)
    {
        int row = tid >> 5, col = (tid & 31) * 8;
        const float* src = &Y[(size_t)(bm + row) * D_SZ + col];
        float4 lo = *(const float4*)src;
        float4 hi = *(const float4*)(src + 4);
        *(uint4*)&Av[row][col] = pack8(lo, hi);
    }
    __syncthreads();

    // ---- phase 0: t = tanh(Y @ W1^T + b1) -> T
    {
        short8 a0[8];
#pragma unroll
        for (int k8 = 0; k8 < 8; ++k8)
            a0[k8] = *(const short8*)&Av[l16][k8 * 32 + quad * 8];
#pragma unroll
        for (int t = 0; t < 8; ++t) {
            const uint4* wb = &W1s[(size_t)((wid * 8 + t) * 8) * 64 + lane];
            f32x4 acc = {0.f, 0.f, 0.f, 0.f};
#pragma unroll
            for (int k8 = 0; k8 < 8; ++k8)
                acc = __builtin_amdgcn_mfma_f32_16x16x32_bf16(
                        a0[k8], as_short8(wb[k8 * 64]), acc, 0, 0, 0);
            const int col = wid * 128 + t * 16 + l16;
            const float bias = b1[col];
#pragma unroll
            for (int r = 0; r < 4; ++r)
                T[quad * 4 + r][col] = f32_to_bf16(fast_tanh(acc[r] + bias));
        }
    }
    __syncthreads();

    // ---- phase 1: v = T @ W2^T + b2 -> V (fp32) and vb -> Av (bf16)
    {
        const uint4* wb0 = &W2s[(size_t)((wid * 2 + 0) * 32) * 64 + lane];
        const uint4* wb1 = &W2s[(size_t)((wid * 2 + 1) * 32) * 64 + lane];
        f32x4 acc0 = {0.f, 0.f, 0.f, 0.f}, acc1 = {0.f, 0.f, 0.f, 0.f};
#pragma unroll
        for (int k8 = 0; k8 < 32; ++k8) {
            short8 a = *(const short8*)&T[l16][k8 * 32 + quad * 8];
            acc0 = __builtin_amdgcn_mfma_f32_16x16x32_bf16(a, as_short8(wb0[k8 * 64]), acc0, 0, 0, 0);
            acc1 = __builtin_amdgcn_mfma_f32_16x16x32_bf16(a, as_short8(wb1[k8 * 64]), acc1, 0, 0, 0);
        }
#pragma unroll
        for (int t2 = 0; t2 < 2; ++t2) {
            f32x4 acc = t2 ? acc1 : acc0;
            const int n = wid * 32 + t2 * 16 + l16;
            const float bb = b2[n];
#pragma unroll
            for (int r = 0; r < 4; ++r) {
                float v = acc[r] + bb;
                V[quad * 4 + r][n]  = v;
                Av[quad * 4 + r][n] = f32_to_bf16(v);
            }
        }
    }
    __syncthreads();

    // ---- phase 2: p = (1-t^2) ⊙ (vb @ W1^T) -> T (in place)
    {
        short8 a2[8];
#pragma unroll
        for (int k8 = 0; k8 < 8; ++k8)
            a2[k8] = *(const short8*)&Av[l16][k8 * 32 + quad * 8];
#pragma unroll
        for (int t = 0; t < 8; ++t) {
            const uint4* wb = &W1s[(size_t)((wid * 8 + t) * 8) * 64 + lane];
            f32x4 acc = {0.f, 0.f, 0.f, 0.f};
#pragma unroll
            for (int k8 = 0; k8 < 8; ++k8)
                acc = __builtin_amdgcn_mfma_f32_16x16x32_bf16(
                        a2[k8], as_short8(wb[k8 * 64]), acc, 0, 0, 0);
            const int col = wid * 128 + t * 16 + l16;
#pragma unroll
            for (int r = 0; r < 4; ++r) {
                float tt = bf16_to_f32(T[quad * 4 + r][col]);
                T[quad * 4 + r][col] = f32_to_bf16((1.f - tt * tt) * acc[r]);
            }
        }
    }
    __syncthreads();

    // ---- phase 3: OUT = V + 0.005 * (p @ W2^T)
    {
        const uint4* wb0 = &W2s[(size_t)((wid * 2 + 0) * 32) * 64 + lane];
        const uint4* wb1 = &W2s[(size_t)((wid * 2 + 1) * 32) * 64 + lane];
        f32x4 acc0 = {0.f, 0.f, 0.f, 0.f}, acc1 = {0.f, 0.f, 0.f, 0.f};
#pragma unroll
        for (int k8 = 0; k8 < 32; ++k8) {
            short8 a = *(const short8*)&T[l16][k8 * 32 + quad * 8];
            acc0 = __builtin_amdgcn_mfma_f32_16x16x32_bf16(a, as_short8(wb0[k8 * 64]), acc0, 0, 0, 0);
            acc1 = __builtin_amdgcn_mfma_f32_16x16x32_bf16(a, as_short8(wb1[k8 * 64]), acc1, 0, 0, 0);
        }
#pragma unroll
        for (int t2 = 0; t2 < 2; ++t2) {
            f32x4 acc = t2 ? acc1 : acc0;
            const int n = wid * 32 + t2 * 16 + l16;
#pragma unroll
            for (int r = 0; r < 4; ++r) {
                const int m = quad * 4 + r;
                OUT[(size_t)(bm + m) * D_SZ + n] = V[m][n] + 0.005f * acc[r];
            }
        }
    }
}

extern "C" void kernel_launch(void* const* d_in, const int* in_sizes, int n_in,
                              void* d_out, int out_size, void* d_ws, size_t ws_size,
                              hipStream_t stream) {
    const float* Y  = (const float*)d_in[0];  // (512, 256)
    const float* W1 = (const float*)d_in[1];  // (1024, 256)
    const float* b1 = (const float*)d_in[2];  // (1024,)
    const float* W2 = (const float*)d_in[3];  // (256, 1024)
    const float* b2 = (const float*)d_in[4];  // (256,)
    float* OUT = (float*)d_out;               // (512, 256)

    uint4* W1s = (uint4*)d_ws;                       // 512 frags x 1KB = 512 KB
    uint4* W2s = W1s + (size_t)512 * 64;             // 512 frags x 1KB = 512 KB

    convert_w<<<256, 256, 0, stream>>>(W1, W2, W1s, W2s);
    fused_chain<<<32, 512, 0, stream>>>(Y, W1s, W2s, b1, b2, OUT);
}

// Round 4
// 80.948 us; speedup vs baseline: 2.8308x; 1.8010x over previous
//
#include <hip/hip_runtime.h>
#include <math.h>

// EulerRosenbrockModel: B=512, D=256, HID=1024, h=0.01
// out = v + 0.005 * W2 (s ⊙ (W1 vb)),  s = 1-t^2, t = tanh(W1 y + b1), v = W2 t + b2
// (Neumann truncation of (I-cJ)^{-1}(I+dJ), exact to ~1e-5 — verified R1-R10.)
//
// R11: R10's wave-autonomous fused chain, rebuilt against the measured
// bottleneck: 85us = 204k cy = 256 loads/wave x ~800 cy -> load latency was
// FULLY SERIALIZED (VGPR cap 128, 2 waves/SIMD, compiler kept ~1 load in
// flight). Fixes:
//   * 1024 thr/block (16 waves): chain halves to 128 loads/wave, TLP 4/SIMD.
//   * explicit depth-8 double-buffer (two named uint4[8] bufs, fully
//     unrolled, static indices): 8 x 1KB always in flight per wave.
//   * raw lgkm-only barriers between phases + cross-phase prefetch: next
//     phase's first fragment group + biases issued before the barrier;
//     no vmcnt(0) drain anywhere in the body.
// Weights pre-swizzled to MFMA-fragment order by convert_w (R10, verified):
// 1KB contiguous per (tile,k-slice) fragment, lane l's 16B at l*16.

#define B_SZ 512
#define D_SZ 256
#define HID_SZ 1024

typedef short short8 __attribute__((ext_vector_type(8)));   // 8 bf16 (4 VGPRs)
typedef float f32x4 __attribute__((ext_vector_type(4)));

__device__ __forceinline__ float bf16_to_f32(unsigned short u) {
    union { unsigned int i; float f; } c; c.i = ((unsigned int)u) << 16; return c.f;
}
__device__ __forceinline__ unsigned short f32_to_bf16(float f) {
    union { float f; unsigned int i; } c; c.f = f;
    unsigned int b = c.i + 0x7FFFu + ((c.i >> 16) & 1u);   // RNE
    return (unsigned short)(b >> 16);
}
__device__ __forceinline__ uint4 pack8(float4 lo, float4 hi) {
    union { unsigned short u[8]; uint4 v; } o;
    o.u[0] = f32_to_bf16(lo.x); o.u[1] = f32_to_bf16(lo.y);
    o.u[2] = f32_to_bf16(lo.z); o.u[3] = f32_to_bf16(lo.w);
    o.u[4] = f32_to_bf16(hi.x); o.u[5] = f32_to_bf16(hi.y);
    o.u[6] = f32_to_bf16(hi.z); o.u[7] = f32_to_bf16(hi.w);
    return o.v;
}
__device__ __forceinline__ float fast_tanh(float x) {
    float e = __expf(2.0f * x);
    return 1.0f - 2.0f / (e + 1.0f);
}
__device__ __forceinline__ short8 as_short8(uint4 u) {
    union { uint4 v; short8 s; } c; c.v = u; return c.s;
}
// lgkm-drain barrier: cross-wave LDS visibility WITHOUT draining vmcnt —
// global loads stay in flight across it (R9-verified correct).
__device__ __forceinline__ void bar_lgkm() {
    asm volatile("s_waitcnt lgkmcnt(0)" ::: "memory");
    __builtin_amdgcn_s_barrier();
    asm volatile("" ::: "memory");
}

// ---- D1: swizzle weights into fragment order, fp32 -> bf16 (R10, verified).
// W1s: frag f1 = t1*8 + ks8   (t1 in [0,64), ks8 in [0,8))
//      lane l: W1[t1*16 + (l&15)][ks8*32 + (l>>4)*8 .. +8]  at f1*1024 + l*16
// W2s: frag f2 = t2*32 + ks8  (t2 in [0,16), ks8 in [0,32))
//      lane l: W2[t2*16 + (l&15)][ks8*32 + (l>>4)*8 .. +8]  at f2*1024 + l*16
__global__ __launch_bounds__(256)
void convert_w(const float* __restrict__ W1, const float* __restrict__ W2,
               uint4* __restrict__ W1s, uint4* __restrict__ W2s)
{
    const int wid  = threadIdx.x >> 6, lane = threadIdx.x & 63;
    const int l16  = lane & 15, quad = lane >> 4;
    const int frag = blockIdx.x * 4 + wid;         // 0..1023
    const float* src;
    uint4* dst;
    if (frag < 512) {
        int t1 = frag >> 3, ks8 = frag & 7;
        src = &W1[(size_t)(t1 * 16 + l16) * D_SZ + ks8 * 32 + quad * 8];
        dst = &W1s[(size_t)frag * 64 + lane];
    } else {
        int f2 = frag - 512;
        int t2 = f2 >> 5, ks8 = f2 & 31;
        src = &W2[(size_t)(t2 * 16 + l16) * HID_SZ + ks8 * 32 + quad * 8];
        dst = &W2s[(size_t)f2 * 64 + lane];
    }
    float4 lo = *(const float4*)src;
    float4 hi = *(const float4*)(src + 4);
    *dst = pack8(lo, hi);
}

// ---- D2: fused chain. 32 blocks x 1024 thr (16 waves). Block owns rows
// bm..bm+15. ph0/ph2: wave w owns hid cols w*64..+64 (4 tiles). ph1/ph3:
// wave w owns out cols w*16..+16 (1 tile, full K=1024 = 32 frags).
__global__ __launch_bounds__(1024, 4)
void fused_chain(const float* __restrict__ Y,
                 const uint4* __restrict__ W1s,
                 const uint4* __restrict__ W2s,
                 const float* __restrict__ b1,
                 const float* __restrict__ b2,
                 float* __restrict__ OUT)
{
    __shared__ alignas(16) unsigned short Av[16][264];   //  8.3 KB  Y bf16, then vb
    __shared__ alignas(16) unsigned short T[16][1032];   // 32.3 KB  t, then p
    __shared__ alignas(16) float V[16][264];             // 16.5 KB  v fp32  (58.4 KB)

    const int tid  = threadIdx.x;
    const int wid  = tid >> 6, lane = tid & 63;          // wid 0..15
    const int l16  = lane & 15, quad = lane >> 4;
    const int bm   = blockIdx.x * 16;

    const uint4* w1b = W1s + lane;
    const uint4* w2b = W2s + lane;

    uint4 bE[8], bO[8];   // depth-8 double buffer (named: static indexing only)

#define LD1(BUF, T_) do { _Pragma("unroll")                                  \
    for (int k = 0; k < 8; ++k)                                              \
        BUF[k] = w1b[((size_t)(wid * 4 + (T_)) * 8 + k) * 64]; } while (0)

#define LD2(BUF, G_) do { _Pragma("unroll")                                  \
    for (int k = 0; k < 8; ++k)                                              \
        BUF[k] = w2b[((size_t)wid * 32 + (G_) * 8 + k) * 64]; } while (0)

#define MFMA8(BUF, AARR) do { acc = (f32x4){0.f,0.f,0.f,0.f}; _Pragma("unroll") \
    for (int k8 = 0; k8 < 8; ++k8)                                           \
        acc = __builtin_amdgcn_mfma_f32_16x16x32_bf16(                       \
                AARR[k8], as_short8(BUF[k8]), acc, 0, 0, 0); } while (0)

#define MM2ACC(BUF, G_) do { _Pragma("unroll")                               \
    for (int k8 = 0; k8 < 8; ++k8) {                                         \
        short8 a = *(const short8*)&T[l16][((G_) * 8 + k8) * 32 + quad * 8]; \
        acc = __builtin_amdgcn_mfma_f32_16x16x32_bf16(                       \
                a, as_short8(BUF[k8]), acc, 0, 0, 0); } } while (0)

#define EPI_T(T_, BIAS) do { int col = wid * 64 + (T_) * 16 + l16;           \
    _Pragma("unroll")                                                        \
    for (int r = 0; r < 4; ++r)                                              \
        T[quad * 4 + r][col] = f32_to_bf16(fast_tanh(acc[r] + (BIAS))); } while (0)

#define EPI_P(T_) do { int col = wid * 64 + (T_) * 16 + l16;                 \
    _Pragma("unroll")                                                        \
    for (int r = 0; r < 4; ++r) {                                            \
        float tt = bf16_to_f32(T[quad * 4 + r][col]);                        \
        T[quad * 4 + r][col] = f32_to_bf16((1.f - tt * tt) * acc[r]); } } while (0)

    LD1(bE, 0);                                    // ph0 tile 0: in flight now

    // bias prefetch (independent loads, hidden under everything)
    float bias0 = b1[wid * 64 +  0 + l16];
    float bias1 = b1[wid * 64 + 16 + l16];
    float bias2 = b1[wid * 64 + 32 + l16];
    float bias3 = b1[wid * 64 + 48 + l16];
    float bb2   = b2[wid * 16 + l16];

    // stage Y [16][256] fp32 -> bf16: row = wid, col = lane*4
    {
        float4 yv = *(const float4*)&Y[(size_t)(bm + wid) * D_SZ + lane * 4];
        union { unsigned short u[4]; uint2 v; } o;
        o.u[0] = f32_to_bf16(yv.x); o.u[1] = f32_to_bf16(yv.y);
        o.u[2] = f32_to_bf16(yv.z); o.u[3] = f32_to_bf16(yv.w);
        *(uint2*)&Av[wid][lane * 4] = o.v;
    }
    bar_lgkm();                                    // Av visible; bE in flight

    f32x4 acc;
    // ---- phase 0: t = tanh(Y @ W1^T + b1) -> T
    {
        LD1(bO, 1);
        short8 a0[8];
#pragma unroll
        for (int k8 = 0; k8 < 8; ++k8)
            a0[k8] = *(const short8*)&Av[l16][k8 * 32 + quad * 8];
        MFMA8(bE, a0); LD1(bE, 2); EPI_T(0, bias0);
        MFMA8(bO, a0); LD1(bO, 3); EPI_T(1, bias1);
        MFMA8(bE, a0); LD2(bE, 0);                 // prefetch ph1 group 0
        EPI_T(2, bias2);
        MFMA8(bO, a0); EPI_T(3, bias3);
    }
    bar_lgkm();                                    // T visible; bE (ph1 g0) in flight

    // ---- phase 1: v = T @ W2^T + b2 -> V fp32, vb -> Av bf16
    {
        LD2(bO, 1);
        acc = (f32x4){0.f,0.f,0.f,0.f};
        MM2ACC(bE, 0); LD2(bE, 2);
        MM2ACC(bO, 1); LD2(bO, 3);
        MM2ACC(bE, 2); LD1(bE, 0);                 // prefetch ph2 tile 0
        MM2ACC(bO, 3);
        const int n = wid * 16 + l16;
#pragma unroll
        for (int r = 0; r < 4; ++r) {
            float v = acc[r] + bb2;
            V[quad * 4 + r][n]  = v;
            Av[quad * 4 + r][n] = f32_to_bf16(v);
        }
    }
    bar_lgkm();                                    // V, Av visible; bE in flight

    // ---- phase 2: p = (1-t^2) ⊙ (vb @ W1^T) -> T (in place)
    {
        LD1(bO, 1);
        short8 a2[8];
#pragma unroll
        for (int k8 = 0; k8 < 8; ++k8)
            a2[k8] = *(const short8*)&Av[l16][k8 * 32 + quad * 8];
        MFMA8(bE, a2); LD1(bE, 2); EPI_P(0);
        MFMA8(bO, a2); LD1(bO, 3); EPI_P(1);
        MFMA8(bE, a2); LD2(bE, 0);                 // prefetch ph3 group 0
        EPI_P(2);
        MFMA8(bO, a2); EPI_P(3);
    }
    bar_lgkm();                                    // p visible; bE in flight

    // ---- phase 3: OUT = V + 0.005 * (p @ W2^T)
    {
        LD2(bO, 1);
        acc = (f32x4){0.f,0.f,0.f,0.f};
        MM2ACC(bE, 0); LD2(bE, 2);
        MM2ACC(bO, 1); LD2(bO, 3);
        MM2ACC(bE, 2);
        MM2ACC(bO, 3);
        const int n = wid * 16 + l16;
#pragma unroll
        for (int r = 0; r < 4; ++r) {
            const int m = quad * 4 + r;
            OUT[(size_t)(bm + m) * D_SZ + n] = V[m][n] + 0.005f * acc[r];
        }
    }
#undef LD1
#undef LD2
#undef MFMA8
#undef MM2ACC
#undef EPI_T
#undef EPI_P
}

extern "C" void kernel_launch(void* const* d_in, const int* in_sizes, int n_in,
                              void* d_out, int out_size, void* d_ws, size_t ws_size,
                              hipStream_t stream) {
    const float* Y  = (const float*)d_in[0];  // (512, 256)
    const float* W1 = (const float*)d_in[1];  // (1024, 256)
    const float* b1 = (const float*)d_in[2];  // (1024,)
    const float* W2 = (const float*)d_in[3];  // (256, 1024)
    const float* b2 = (const float*)d_in[4];  // (256,)
    float* OUT = (float*)d_out;               // (512, 256)

    uint4* W1s = (uint4*)d_ws;                       // 512 frags x 1KB = 512 KB
    uint4* W2s = W1s + (size_t)512 * 64;             // 512 frags x 1KB = 512 KB

    convert_w<<<256, 256, 0, stream>>>(W1, W2, W1s, W2s);
    fused_chain<<<32, 1024, 0, stream>>>(Y, W1s, W2s, b1, b2, OUT);
}